// Round 12
// baseline (300.035 us; speedup 1.0000x reference)
//
#include <hip/hip_runtime.h>
#include <math.h>

// ---------------------------------------------------------------------------
// SAGPool GNN forward: 3x [GCNConv -> SAGPool(top-k) -> readout] + MLP head.
// B=32 graphs x N=2048 nodes; E=524288; 128 feats; K = 1024/512/256.
// R24 changes vs R23 (281.7us best):
//   - k_agg gather de-branched: the `if (cv!=0)` guard serialized the 8-deep
//     row loads (load->branch->load). cv=0 x finite stale row = 0 exactly
//     (dropped nodes' t rows are stale-but-finite; ds=0 zeroes them), so the
//     guard is removed -> 8 outstanding 512B gathers per wave.
//   - everything else byte-identical to R23 (mm frozen, csr+norm piggyback,
//     extracted score, 3-pass radix pool, fused head).
// ---------------------------------------------------------------------------

namespace {

constexpr int B_  = 32;
constexpr int N_  = 2048;
constexpr int NT  = B_ * N_;        // 65536
constexpr int EPG = 16384;
constexpr int E_  = B_ * EPG;       // 524288
constexpr int NCLS = 10;
constexpr int AST = 132;            // A-tile LDS row stride (128 + 4 pad)

// logical block id -> tile, grouping graphs g%8 per XCD (id%8=XCD).
__device__ __forceinline__ int relabel(int bid, int bpgsh) {
  int x = bid & 7, slot = bid >> 3;
  int g = x + 8 * (slot >> bpgsh);
  return (g << bpgsh) + (slot & ((1 << bpgsh) - 1));
}

// ---- CSR build + layer-0 norm, 512-thread variant (runs inside mm0 grid) --
__device__ void csr_build(const int* __restrict__ src, const int* __restrict__ dst,
                          int* __restrict__ off, int* __restrict__ srcp,
                          float* __restrict__ dinv, float* __restrict__ ds,
                          float* __restrict__ sws, int* hist) {
  const int g = blockIdx.x;    // blocks 0..31, %8 = XCD = g%8
  const int t = threadIdx.x;   // 0..511
  const int base_n = g * N_;
  const int base_e = g * EPG;
  int* wsum8 = hist + 2048;
#pragma unroll
  for (int i = 0; i < 4; ++i) hist[t + 512 * i] = 0;
  __syncthreads();
  for (int i = 0; i < EPG / 512; i += 8) {
    int dd[8];
#pragma unroll
    for (int j = 0; j < 8; ++j) dd[j] = dst[base_e + t + 512 * (i + j)];
#pragma unroll
    for (int j = 0; j < 8; ++j) atomicAdd(&hist[dd[j] - base_n], 1);
  }
  __syncthreads();
  int a[4], ssum = 0;
#pragma unroll
  for (int i = 0; i < 4; ++i) { a[i] = hist[4 * t + i]; ssum += a[i]; }
  {
    int lane = t & 63, w = t >> 6;   // 8 waves
    int v = ssum;
#pragma unroll
    for (int o = 1; o < 64; o <<= 1) {
      int nv = __shfl_up(v, o);
      if (lane >= o) v += nv;
    }
    if (lane == 63) wsum8[w] = v;
    __syncthreads();
    if (t == 0) {
      int accv = 0;
      for (int i = 0; i < 8; ++i) { int tmp = wsum8[i]; wsum8[i] = accv; accv += tmp; }
    }
    __syncthreads();
    int run = wsum8[w] + v - ssum;
#pragma unroll
    for (int i = 0; i < 4; ++i) {
      int n = 4 * t + i;
      off[base_n + n] = base_e + run;
      hist[n] = run;                 // LDS cursor (own bins only: safe)
      float d0 = 1.f + (float)a[i];  // deg = 1 + indegree (layer-0 masks = 1)
      float di0 = 1.f / sqrtf(d0);
      dinv[base_n + n] = di0;
      ds[base_n + n] = di0;
      sws[base_n + n] = di0 * di0;
      run += a[i];
    }
    if (g == B_ - 1 && t == 0) off[NT] = E_;
  }
  __syncthreads();
  for (int i = 0; i < EPG / 512; i += 8) {
    int dd[8], ss[8];
#pragma unroll
    for (int j = 0; j < 8; ++j) {
      int e = base_e + t + 512 * (i + j);
      dd[j] = dst[e];
      ss[j] = src[e];
    }
#pragma unroll
    for (int j = 0; j < 8; ++j) {
      int slot = atomicAdd(&hist[dd[j] - base_n], 1);
      srcp[base_e + slot] = ss[j];
    }
  }
}

// ---- norm role (512 thr, 64 nodes x 8 lanes), piggybacked on mm(l+1) ------
__device__ void norm_body(const int* __restrict__ off,
                          const int* __restrict__ srcp,
                          const float* __restrict__ kpmask,
                          const float* __restrict__ scale,
                          float* __restrict__ dinv,
                          float* __restrict__ ds,
                          float* __restrict__ sws,
                          const int* __restrict__ nkept,
                          int nkshift, int nbpgsh, int nb) {
  int q = relabel(nb, nbpgsh) * 64 + ((int)threadIdx.x >> 3);
  int g = q >> nkshift;
  int node = nkept[g * N_ + (q - (g << nkshift))];
  const int lane = threadIdx.x & 7;
  int s = off[node], en = off[node + 1];
  float d = (lane == 0) ? 1.f : 0.f;
  for (int j = s + lane; j < en; j += 8) d += kpmask[srcp[j]];
#pragma unroll
  for (int o = 4; o >= 1; o >>= 1) d += __shfl_down(d, o, 8);
  if (lane == 0) {
    float di = 1.f / sqrtf(d);
    float sc = scale[node];
    dinv[node] = di;
    ds[node] = di * sc;
    sws[node] = di * di * sc;
  }
}

// ---- dense matmul + fused readout; 3 block roles: [csr | mm | norm] --------
__global__ __launch_bounds__(512) void k_matmul(const float* __restrict__ A,
                                                const float* __restrict__ W,
                                                float* __restrict__ C,
                                                const int* __restrict__ kept,
                                                int kshift, int bpgsh, int mmBlocks,
                                                const float* __restrict__ scaleArr,
                                                float* __restrict__ pmx,
                                                float* __restrict__ psm,
                                                const int* __restrict__ src,
                                                const int* __restrict__ dst,
                                                int* __restrict__ off,
                                                int* __restrict__ srcp,
                                                float* __restrict__ dinvW,
                                                float* __restrict__ dsW,
                                                float* __restrict__ swsW,
                                                int csrBlocks,
                                                const float* __restrict__ kpmask,
                                                const int* __restrict__ nkept,
                                                int nkshift, int nbpgsh) {
  __shared__ float Ast[2][32 * AST];   // 33.8 KB
  __shared__ float Ws[2][32 * 128];    // 32.8 KB
  __shared__ int rowid[128];
  __shared__ float rsc[128];
  if ((int)blockIdx.x < csrBlocks) {
    csr_build(src, dst, off, srcp, dinvW, dsW, swsW, (int*)&Ast[0][0]);
    return;
  }
  if ((int)blockIdx.x >= csrBlocks + mmBlocks) {
    norm_body(off, srcp, kpmask, scaleArr, dinvW, dsW, swsW, nkept,
              nkshift, nbpgsh, (int)blockIdx.x - csrBlocks - mmBlocks);
    return;
  }
  const int tid = threadIdx.x;   // 0..511
  const int tile = relabel((int)blockIdx.x - csrBlocks, bpgsh);
  if (kept) {
    if (tid < 128) {
      int q = tile * 128 + tid;
      int g = q >> kshift;
      int row = kept[g * N_ + (q - (g << kshift))];
      rowid[tid] = row;
      rsc[tid] = scaleArr[row];
    }
    __syncthreads();
  }
  const int rowq = tid >> 4;   // 0..31: rows 4*rowq..+3
  const int colq = tid & 15;   // cols {4c..4c+3, 64+4c..+3}
  float4 va[2], vw[2];
#pragma unroll
  for (int i = 0; i < 2; ++i) {
    int idx = tid + 512 * i;
    int row = idx >> 3, f4 = idx & 7;
    int grw = kept ? rowid[row] : tile * 128 + row;
    va[i] = *(const float4*)&A[(size_t)grw * 128 + 4 * f4];
  }
#pragma unroll
  for (int i = 0; i < 2; ++i) {
    int idx = tid + 512 * i;
    int kk = idx >> 5, cf = idx & 31;
    vw[i] = *(const float4*)&W[(size_t)kk * 128 + 4 * cf];
  }
#pragma unroll
  for (int i = 0; i < 2; ++i) {
    int idx = tid + 512 * i;
    int row = idx >> 3, f4 = idx & 7;
    Ast[0][(4 * f4 + 0) * AST + row] = va[i].x;
    Ast[0][(4 * f4 + 1) * AST + row] = va[i].y;
    Ast[0][(4 * f4 + 2) * AST + row] = va[i].z;
    Ast[0][(4 * f4 + 3) * AST + row] = va[i].w;
  }
#pragma unroll
  for (int i = 0; i < 2; ++i) {
    int idx = tid + 512 * i;
    int kk = idx >> 5, cf = idx & 31;
    *(float4*)&Ws[0][kk * 128 + 4 * cf] = vw[i];
  }
  __syncthreads();
  float acc[4][8] = {};
  for (int c = 0; c < 4; ++c) {
    int cur = c & 1;
    if (c < 3) {
      int k0n = 32 * (c + 1);
#pragma unroll
      for (int i = 0; i < 2; ++i) {
        int idx = tid + 512 * i;
        int row = idx >> 3, f4 = idx & 7;
        int grw = kept ? rowid[row] : tile * 128 + row;
        va[i] = *(const float4*)&A[(size_t)grw * 128 + k0n + 4 * f4];
      }
#pragma unroll
      for (int i = 0; i < 2; ++i) {
        int idx = tid + 512 * i;
        int kk = idx >> 5, cf = idx & 31;
        vw[i] = *(const float4*)&W[(size_t)(k0n + kk) * 128 + 4 * cf];
      }
    }
#pragma unroll 2
    for (int kk = 0; kk < 32; ++kk) {
      float4 a0 = *(const float4*)&Ast[cur][kk * AST + 4 * rowq];
      float4 w0 = *(const float4*)&Ws[cur][kk * 128 + 4 * colq];
      float4 w1 = *(const float4*)&Ws[cur][kk * 128 + 64 + 4 * colq];
      float a[4] = {a0.x, a0.y, a0.z, a0.w};
      float w[8] = {w0.x, w0.y, w0.z, w0.w, w1.x, w1.y, w1.z, w1.w};
#pragma unroll
      for (int r = 0; r < 4; ++r)
#pragma unroll
        for (int cc = 0; cc < 8; ++cc) acc[r][cc] += a[r] * w[cc];
    }
    // fused readout of this chunk's 32 feats from the staged tile
    if (kept) {
      int kkf = tid >> 4;            // feat within chunk, 0..31
      int r0 = (tid & 15) * 8;       // 8-row slice per thread
      float mxv = -INFINITY, smv = 0.f;
#pragma unroll
      for (int rr = 0; rr < 8; rr += 4) {
        float4 av = *(const float4*)&Ast[cur][kkf * AST + r0 + rr];
        float4 s4 = *(const float4*)&rsc[r0 + rr];
        float v0 = av.x * s4.x, v1 = av.y * s4.y;
        float v2 = av.z * s4.z, v3 = av.w * s4.w;
        mxv = fmaxf(fmaxf(fmaxf(mxv, v0), fmaxf(v1, v2)), v3);
        smv += v0 + v1 + v2 + v3;
      }
#pragma unroll
      for (int o = 8; o >= 1; o >>= 1) {
        mxv = fmaxf(mxv, __shfl_down(mxv, o, 16));
        smv += __shfl_down(smv, o, 16);
      }
      if ((tid & 15) == 0) {
        pmx[(size_t)tile * 128 + 32 * c + kkf] = mxv;
        psm[(size_t)tile * 128 + 32 * c + kkf] = smv;
      }
    }
    if (c < 3) {
      int nxt = cur ^ 1;
#pragma unroll
      for (int i = 0; i < 2; ++i) {
        int idx = tid + 512 * i;
        int row = idx >> 3, f4 = idx & 7;
        Ast[nxt][(4 * f4 + 0) * AST + row] = va[i].x;
        Ast[nxt][(4 * f4 + 1) * AST + row] = va[i].y;
        Ast[nxt][(4 * f4 + 2) * AST + row] = va[i].z;
        Ast[nxt][(4 * f4 + 3) * AST + row] = va[i].w;
      }
#pragma unroll
      for (int i = 0; i < 2; ++i) {
        int idx = tid + 512 * i;
        int kk = idx >> 5, cf = idx & 31;
        *(float4*)&Ws[nxt][kk * 128 + 4 * cf] = vw[i];
      }
      __syncthreads();
    }
  }
#pragma unroll
  for (int r = 0; r < 4; ++r) {
    int grw = kept ? rowid[4 * rowq + r] : tile * 128 + 4 * rowq + r;
    float* Crow = &C[(size_t)grw * 128];
    *(float4*)&Crow[4 * colq] = make_float4(acc[r][0], acc[r][1], acc[r][2], acc[r][3]);
    *(float4*)&Crow[64 + 4 * colq] = make_float4(acc[r][4], acc[r][5], acc[r][6], acc[r][7]);
  }
}

// ---- feature aggregation + bias + relu + fused score matvec ----------------
// R24: gather loop de-branched (cv=0 x finite stale row = 0 exactly).
__global__ __launch_bounds__(256) void k_agg(const float4* __restrict__ t4,
                                             const int* __restrict__ off,
                                             const int* __restrict__ srcp,
                                             const float* __restrict__ dinv,
                                             const float* __restrict__ ds,
                                             const float* __restrict__ sws,
                                             const float* __restrict__ bias,
                                             const float* __restrict__ Wp,
                                             float4* __restrict__ h4,
                                             float* __restrict__ t1,
                                             const int* __restrict__ kept,
                                             int kshift, int bpgsh) {
  int q = relabel(blockIdx.x, bpgsh) * 8 + (threadIdx.x >> 5);
  int node;
  if (kept) {
    int g = q >> kshift;
    node = kept[g * N_ + (q - (g << kshift))];
  } else {
    node = q;
  }
  const int lane = threadIdx.x & 31;
  const float dvi = dinv[node];
  float sw = sws[node];
  float4 self = t4[(size_t)node * 32 + lane];
  float4 acc = make_float4(sw * self.x, sw * self.y, sw * self.z, sw * self.w);
  int s = off[node], en = off[node + 1];
  int j = s;
  for (; j + 8 <= en; j += 8) {
    int sv[8];
    float cv[8];
    float4 rv[8];
#pragma unroll
    for (int i = 0; i < 8; ++i) sv[i] = srcp[j + i];
#pragma unroll
    for (int i = 0; i < 8; ++i) rv[i] = t4[(size_t)sv[i] * 32 + lane];
#pragma unroll
    for (int i = 0; i < 8; ++i) cv[i] = ds[sv[i]] * dvi;
#pragma unroll
    for (int i = 0; i < 8; ++i) {
      acc.x += cv[i] * rv[i].x; acc.y += cv[i] * rv[i].y;
      acc.z += cv[i] * rv[i].z; acc.w += cv[i] * rv[i].w;
    }
  }
  for (; j < en; ++j) {
    int s0 = srcp[j];
    float4 r0 = t4[(size_t)s0 * 32 + lane];
    float c0 = ds[s0] * dvi;
    acc.x += c0 * r0.x; acc.y += c0 * r0.y; acc.z += c0 * r0.z; acc.w += c0 * r0.w;
  }
  float4 b4 = ((const float4*)bias)[lane];
  acc.x = fmaxf(acc.x + b4.x, 0.f);
  acc.y = fmaxf(acc.y + b4.y, 0.f);
  acc.z = fmaxf(acc.z + b4.z, 0.f);
  acc.w = fmaxf(acc.w + b4.w, 0.f);
  h4[(size_t)node * 32 + lane] = acc;
  float4 wp = ((const float4*)Wp)[lane];
  float part = acc.x * wp.x + acc.y * wp.y + acc.z * wp.z + acc.w * wp.w;
#pragma unroll
  for (int o = 16; o > 0; o >>= 1) part += __shfl_down(part, o, 32);
  if (lane == 0) t1[node] = part;
}

// ---- score aggregation: 8 lanes/node ---------------------------------------
__global__ __launch_bounds__(256) void k_score(const float* __restrict__ t1,
                                               const int* __restrict__ off,
                                               const int* __restrict__ srcp,
                                               const float* __restrict__ dinv,
                                               const float* __restrict__ bp,
                                               float* __restrict__ raw,
                                               const int* __restrict__ kept,
                                               int kshift, int bpgsh) {
  int q = relabel(blockIdx.x, bpgsh) * 32 + (threadIdx.x >> 3);
  int node;
  if (kept) {
    int g = q >> kshift;
    node = kept[g * N_ + (q - (g << kshift))];
  } else {
    node = q;
  }
  const int lane = threadIdx.x & 7;
  int s = off[node], en = off[node + 1];
  float a = 0.f;
  for (int j = s + lane; j < en; j += 8) {
    int sl = srcp[j];
    a += dinv[sl] * t1[sl];
  }
#pragma unroll
  for (int o = 4; o >= 1; o >>= 1) a += __shfl_down(a, o, 8);
  if (lane == 0) {
    float di = dinv[node];
    raw[node] = di * di * t1[node] + di * a + bp[0];
  }
}

// ---- pool: 3-pass radix top-k + compact + mask writes (+readout+head) ------
__global__ __launch_bounds__(1024) void k_pool(const float* __restrict__ raw,
                                               float* __restrict__ dinv,
                                               float* __restrict__ ds,
                                               float* __restrict__ sws,
                                               float* __restrict__ scale,
                                               float* __restrict__ kpmask,
                                               int* __restrict__ kept,
                                               const float4* __restrict__ h4,
                                               float invk, int k,
                                               const int* __restrict__ inKept, int klen,
                                               const float* __restrict__ pmxA,
                                               const float* __restrict__ psmA,
                                               const float* __restrict__ pmxB,
                                               const float* __restrict__ psmB,
                                               const float* __restrict__ hW1,
                                               const float* __restrict__ hb1,
                                               const float* __restrict__ hW2,
                                               const float* __restrict__ hb2,
                                               const float* __restrict__ hW3,
                                               const float* __restrict__ hb3,
                                               float* __restrict__ out) {
  __shared__ float st1[2048];       // scale after selection (readout)
  __shared__ float skp[2048];
  __shared__ int skept[1024];
  __shared__ unsigned rephist[4096];  // radix bins; reused as red[] in readout
  __shared__ unsigned ebits[64];
  __shared__ int wsum[16];
  __shared__ unsigned bc_digit, bc_prev;
  __shared__ float gr[256], o1[128], o2[64], o3[NCLS];
  const int g = (blockIdx.x & 7) + 8 * (blockIdx.x >> 3);
  const int t = threadIdx.x;
  const int base = g * N_;
  st1[t] = 0.f;
  st1[t + 1024] = 0.f;
  skp[t] = 0.f;
  skp[t + 1024] = 0.f;
  if (t < 64) ebits[t] = 0u;
  __syncthreads();
  int nodeq[2] = {-1, -1};
  float rawv[2] = {0.f, 0.f};
  unsigned key[2] = {0xFFFFFFFFu, 0xFFFFFFFFu};
#pragma unroll
  for (int q = 0; q < 2; ++q) {
    int i = t + q * 1024;
    if (i >= klen) continue;
    int n = inKept ? (inKept[base + i] - base) : i;
    nodeq[q] = n;
    float r = raw[base + n];
    rawv[q] = r;
    unsigned u = __float_as_uint(r);
    u = (u & 0x80000000u) ? ~u : (u | 0x80000000u);
    u = ~u;  // descending
    key[q] = u;
  }
  // 3-pass radix select of k-th largest: bits [31:21], [20:10], [9:0].
  // Single LDS-atomic histogram (2048 keys -> ~1 hit/bin).
  unsigned prefix = 0u, rem = (unsigned)k;
  const int SH0 = 21, SH1 = 10, SH2 = 0;
  for (int p = 0; p < 3; ++p) {
    const int shift = (p == 0) ? SH0 : (p == 1 ? SH1 : SH2);
    const int nb = (p == 2) ? 1024 : 2048;
    const unsigned mask = (p == 0) ? 0u
                        : (p == 1 ? (0xFFFFFFFFu << SH0) : (0xFFFFFFFFu << SH1));
    rephist[t] = 0u;
    rephist[t + 1024] = 0u;
    __syncthreads();
#pragma unroll
    for (int q = 0; q < 2; ++q)
      if (nodeq[q] >= 0 && (key[q] & mask) == prefix)
        atomicAdd(&rephist[(key[q] >> shift) & (unsigned)(nb - 1)], 1u);
    __syncthreads();
    unsigned b0, b1;
    if (nb == 2048) { b0 = rephist[2 * t]; b1 = rephist[2 * t + 1]; }
    else           { b0 = rephist[t];     b1 = 0u; }
    unsigned ps = b0 + b1;
    {
      int lane = t & 63, w = t >> 6;
      unsigned v = ps;
#pragma unroll
      for (int o = 1; o < 64; o <<= 1) {
        unsigned nv = __shfl_up(v, o);
        if (lane >= o) v += nv;
      }
      if (lane == 63) wsum[w] = (int)v;
      __syncthreads();
      if (t == 0) {
        int accv = 0;
        for (int i = 0; i < 16; ++i) { int tmp = wsum[i]; wsum[i] = accv; accv += tmp; }
      }
      __syncthreads();
      unsigned exc = (unsigned)wsum[w] + v - ps;
      if (exc < rem && exc + b0 >= rem) {
        bc_digit = (unsigned)((nb == 2048) ? 2 * t : t);
        bc_prev = exc;
      }
      if (nb == 2048 && exc + b0 < rem && exc + b0 + b1 >= rem) {
        bc_digit = (unsigned)(2 * t + 1);
        bc_prev = exc + b0;
      }
    }
    __syncthreads();
    prefix |= bc_digit << shift;
    rem -= bc_prev;
  }
  const unsigned Tkey = prefix;
  const int need = (int)rem;  // ties, lowest index first
#pragma unroll
  for (int q = 0; q < 2; ++q) {
    int n = nodeq[q];
    if (n >= 0 && key[q] == Tkey) atomicOr(&ebits[n >> 5], 1u << (n & 31));
  }
  __syncthreads();
#pragma unroll
  for (int q = 0; q < 2; ++q) {
    int n = nodeq[q];
    if (n < 0) continue;
    float kp;
    if (key[q] < Tkey) {
      kp = 1.f;
    } else if (key[q] == Tkey) {
      int w = n >> 5;
      int rank = __popc(ebits[w] & ((1u << (n & 31)) - 1u));
      for (int u = 0; u < w; ++u) rank += __popc(ebits[u]);
      kp = (rank < need) ? 1.f : 0.f;
    } else {
      kp = 0.f;
    }
    skp[n] = kp;
    float sc = kp * tanhf(rawv[q]);
    st1[n] = sc;
    scale[base + n] = sc;
    kpmask[base + n] = kp;
    if (kp == 0.f) {            // dropped: zero masks for next layer's gathers
      dinv[base + n] = 0.f;
      ds[base + n] = 0.f;
      sws[base + n] = 0.f;
    }
  }
  __syncthreads();
  // compacted kept list -> global + LDS
  {
    int lane = t & 63, w = t >> 6;
    int a0 = (int)skp[2 * t], a1 = (int)skp[2 * t + 1];
    int ps = a0 + a1;
    int v = ps;
#pragma unroll
    for (int o = 1; o < 64; o <<= 1) {
      int nv = __shfl_up(v, o);
      if (lane >= o) v += nv;
    }
    if (lane == 63) wsum[w] = v;
    __syncthreads();
    if (t == 0) {
      int accv = 0;
      for (int i = 0; i < 16; ++i) { int tmp = wsum[i]; wsum[i] = accv; accv += tmp; }
    }
    __syncthreads();
    int excl = wsum[w] + v - ps;
    if (a0) { kept[base + excl] = base + 2 * t; skept[excl] = base + 2 * t; }
    if (a1) { kept[base + excl + a0] = base + 2 * t + 1; skept[excl + a0] = base + 2 * t + 1; }
  }
  if (!out) return;
  __syncthreads();
  // layer-3 readout over kept list
  const int lane = t & 31, ng = t >> 5;
  float4 mx = make_float4(-INFINITY, -INFINITY, -INFINITY, -INFINITY);
  float4 sm = make_float4(0.f, 0.f, 0.f, 0.f);
  for (int i = ng; i < k; i += 32) {
    int node = skept[i];
    float sc = st1[node - base];
    float4 v = h4[(size_t)node * 32 + lane];
    v.x *= sc; v.y *= sc; v.z *= sc; v.w *= sc;
    mx.x = fmaxf(mx.x, v.x); mx.y = fmaxf(mx.y, v.y);
    mx.z = fmaxf(mx.z, v.z); mx.w = fmaxf(mx.w, v.w);
    sm.x += v.x; sm.y += v.y; sm.z += v.z; sm.w += v.w;
  }
  float4* red = (float4*)rephist;
  for (int d = 16; d >= 1; d >>= 1) {
    if (ng >= d && ng < 2 * d) {
      red[(ng - d) * 32 + lane] = mx;
      red[512 + (ng - d) * 32 + lane] = sm;
    }
    __syncthreads();
    if (ng < d) {
      float4 omx = red[ng * 32 + lane];
      float4 osm = red[512 + ng * 32 + lane];
      mx.x = fmaxf(mx.x, omx.x); mx.y = fmaxf(mx.y, omx.y);
      mx.z = fmaxf(mx.z, omx.z); mx.w = fmaxf(mx.w, omx.w);
      sm.x += osm.x; sm.y += osm.y; sm.z += osm.z; sm.w += osm.w;
    }
    __syncthreads();
  }
  if (ng == 0) {
    gr[4 * lane + 0] = mx.x;
    gr[4 * lane + 1] = mx.y;
    gr[4 * lane + 2] = mx.z;
    gr[4 * lane + 3] = mx.w;
    gr[128 + 4 * lane + 0] = sm.x * invk;
    gr[128 + 4 * lane + 1] = sm.y * invk;
    gr[128 + 4 * lane + 2] = sm.z * invk;
    gr[128 + 4 * lane + 3] = sm.w * invk;
  }
  __syncthreads();
  // fused MLP head + log_softmax
  if (t < 128) {
    float mxA = -INFINITY, smA = 0.f;
#pragma unroll
    for (int p = 0; p < 8; ++p) {
      mxA = fmaxf(mxA, pmxA[(size_t)(g * 8 + p) * 128 + t]);
      smA += psmA[(size_t)(g * 8 + p) * 128 + t];
    }
    float mxB = -INFINITY, smB = 0.f;
#pragma unroll
    for (int p = 0; p < 4; ++p) {
      mxB = fmaxf(mxB, pmxB[(size_t)(g * 4 + p) * 128 + t]);
      smB += psmB[(size_t)(g * 4 + p) * 128 + t];
    }
    gr[t] += mxA + mxB;
    gr[t + 128] += smA * (1.f / 1024.f) + smB * (1.f / 512.f);
  }
  __syncthreads();
  if (t < 128) {
    float a = hb1[t];
    for (int kk = 0; kk < 256; ++kk) a += gr[kk] * hW1[kk * 128 + t];
    o1[t] = fmaxf(a, 0.f);
  }
  __syncthreads();
  if (t < 64) {
    float a2 = hb2[t];
    for (int kk = 0; kk < 128; ++kk) a2 += o1[kk] * hW2[kk * 64 + t];
    o2[t] = fmaxf(a2, 0.f);
  }
  __syncthreads();
  if (t < NCLS) {
    float a3 = hb3[t];
    for (int kk = 0; kk < 64; ++kk) a3 += o2[kk] * hW3[kk * NCLS + t];
    o3[t] = a3;
  }
  __syncthreads();
  if (t == 0) {
    float m = -INFINITY;
    for (int c = 0; c < NCLS; ++c) m = fmaxf(m, o3[c]);
    float sum = 0.f;
    for (int c = 0; c < NCLS; ++c) sum += expf(o3[c] - m);
    float lse = logf(sum);
    for (int c = 0; c < NCLS; ++c) out[g * NCLS + c] = o3[c] - m - lse;
  }
}

}  // namespace

extern "C" void kernel_launch(void* const* d_in, const int* in_sizes, int n_in,
                              void* d_out, int out_size, void* d_ws, size_t ws_size,
                              hipStream_t stream) {
  const float* x = (const float*)d_in[0];
  const int* ei = (const int*)d_in[1];
  const int* src = ei;
  const int* dst = ei + E_;
  const float* Wl[3]  = {(const float*)d_in[3], (const float*)d_in[7], (const float*)d_in[11]};
  const float* bl[3]  = {(const float*)d_in[4], (const float*)d_in[8], (const float*)d_in[12]};
  const float* Wpl[3] = {(const float*)d_in[5], (const float*)d_in[9], (const float*)d_in[13]};
  const float* bpl[3] = {(const float*)d_in[6], (const float*)d_in[10], (const float*)d_in[14]};
  const float* l1W = (const float*)d_in[15];
  const float* l1b = (const float*)d_in[16];
  const float* l2W = (const float*)d_in[17];
  const float* l2b = (const float*)d_in[18];
  const float* l3W = (const float*)d_in[19];
  const float* l3b = (const float*)d_in[20];

  char* p = (char*)d_ws;
  auto alloc = [&](size_t bytes) -> void* {
    void* r = (void*)p;
    p += (bytes + 255) & ~size_t(255);
    return r;
  };
  float* h      = (float*)alloc((size_t)NT * 128 * 4);
  float* t      = (float*)alloc((size_t)NT * 128 * 4);
  float* dinv   = (float*)alloc(NT * 4);
  float* ds     = (float*)alloc(NT * 4);
  float* sws    = (float*)alloc(NT * 4);
  float* scale  = (float*)alloc(NT * 4);
  float* t1     = (float*)alloc(NT * 4);
  float* raw    = (float*)alloc(NT * 4);
  float* kpmask = (float*)alloc(NT * 4);
  int*   srcp   = (int*)alloc(E_ * 4);
  int*   off    = (int*)alloc((NT + 1) * 4);
  int*   kept0  = (int*)alloc(NT * 4);
  int*   kept1  = (int*)alloc(NT * 4);
  int*   kept2  = (int*)alloc(NT * 4);
  float* pmxA   = (float*)alloc(256 * 128 * 4);
  float* psmA   = (float*)alloc(256 * 128 * 4);
  float* pmxB   = (float*)alloc(128 * 128 * 4);
  float* psmB   = (float*)alloc(128 * 128 * 4);

  int* keptL[3] = {kept0, kept1, kept2};
  const int K[3] = {1024, 512, 256};
  const int KSH[3] = {10, 9, 8};
  float* pmxL[3] = {nullptr, pmxA, pmxB};
  float* psmL[3] = {nullptr, psmA, psmB};

  const float* inF = x;
  for (int l = 0; l < 3; ++l) {
    const int* inKept = (l == 0) ? nullptr : keptL[l - 1];
    int inKsh = (l == 0) ? 11 : KSH[l - 1];
    int nrows = (l == 0) ? NT : B_ * K[l - 1];
    int mmB = nrows / 128;
    int mm_bpgsh = (l == 0) ? 4 : (l == 1 ? 3 : 2);   // 512/256/128 mm blocks
    int ag_bpgsh = (l == 0) ? 8 : (l == 1 ? 7 : 6);   // 8192/4096/2048 blocks
    int sc_bpgsh = (l == 0) ? 6 : (l == 1 ? 5 : 4);   // 2048/1024/512 blocks
    int csrB = (l == 0) ? B_ : 0;                     // csr piggybacks on mm0
    // norm of layer l-1 piggybacks on mm(l): 64 nodes/block (512 thr, 8 lanes)
    int normB = (l == 0) ? 0 : (B_ * K[l - 1]) / 64;  // 512 / 256 blocks
    int nbpgsh = (l == 1) ? 4 : 3;                    // 16 / 8 blocks per graph
    int klen = (l == 0) ? N_ : K[l - 1];
    bool last = (l == 2);
    k_matmul<<<csrB + mmB + normB, 512, 0, stream>>>(
        inF, Wl[l], t, inKept, inKsh, mm_bpgsh, mmB, scale, pmxL[l], psmL[l],
        src, dst, off, srcp, dinv, ds, sws, csrB,
        kpmask, inKept, inKsh, nbpgsh);
    k_agg<<<nrows / 8, 256, 0, stream>>>((const float4*)t, off, srcp, dinv, ds, sws,
                                         bl[l], Wpl[l], (float4*)h, t1, inKept, inKsh,
                                         ag_bpgsh);
    k_score<<<nrows / 32, 256, 0, stream>>>(t1, off, srcp, dinv, bpl[l], raw,
                                            inKept, inKsh, sc_bpgsh);
    k_pool<<<B_, 1024, 0, stream>>>(raw, dinv, ds, sws, scale, kpmask,
                                    keptL[l], (const float4*)h,
                                    1.f / (float)K[l], K[l], inKept, klen,
                                    last ? pmxA : nullptr, last ? psmA : nullptr,
                                    last ? pmxB : nullptr, last ? psmB : nullptr,
                                    l1W, l1b, l2W, l2b, l3W, l3b,
                                    last ? (float*)d_out : nullptr);
    inF = h;
  }
}

// Round 13
// 279.182 us; speedup vs baseline: 1.0747x; 1.0747x over previous
//
#include <hip/hip_runtime.h>
#include <math.h>

// ---------------------------------------------------------------------------
// SAGPool GNN forward: 3x [GCNConv -> SAGPool(top-k) -> readout] + MLP head.
// B=32 graphs x N=2048 nodes; E=524288; 128 feats; K = 1024/512/256.
// R25 changes vs R23 (281.7us best; R24's guard removal REVERTED: the guard
// is load-elision for dropped neighbors, removing it cost +18us):
//   - per-layer edge-list compaction (filter_adj): 4th block role on the
//     mm(l+1) grid filters each kept node's source list by dinv>0 into a
//     ping-pong buffer (srcp<->srcpB) + per-node end pointer dend[].
//     In-segment compaction (same off[] starts) -> no prefix sum.
//     agg/score/norm at l1/l2 then iterate ~1/2 resp ~1/4 the edges.
//   - agg guard restored (R23 form). mm/csr/pool/head byte-identical to R23.
// ---------------------------------------------------------------------------

namespace {

constexpr int B_  = 32;
constexpr int N_  = 2048;
constexpr int NT  = B_ * N_;        // 65536
constexpr int EPG = 16384;
constexpr int E_  = B_ * EPG;       // 524288
constexpr int NCLS = 10;
constexpr int AST = 132;            // A-tile LDS row stride (128 + 4 pad)

// logical block id -> tile, grouping graphs g%8 per XCD (id%8=XCD).
__device__ __forceinline__ int relabel(int bid, int bpgsh) {
  int x = bid & 7, slot = bid >> 3;
  int g = x + 8 * (slot >> bpgsh);
  return (g << bpgsh) + (slot & ((1 << bpgsh) - 1));
}

// ---- CSR build + layer-0 norm, 512-thread variant (runs inside mm0 grid) --
__device__ void csr_build(const int* __restrict__ src, const int* __restrict__ dst,
                          int* __restrict__ off, int* __restrict__ srcp,
                          float* __restrict__ dinv, float* __restrict__ ds,
                          float* __restrict__ sws, int* hist) {
  const int g = blockIdx.x;    // blocks 0..31, %8 = XCD = g%8
  const int t = threadIdx.x;   // 0..511
  const int base_n = g * N_;
  const int base_e = g * EPG;
  int* wsum8 = hist + 2048;
#pragma unroll
  for (int i = 0; i < 4; ++i) hist[t + 512 * i] = 0;
  __syncthreads();
  for (int i = 0; i < EPG / 512; i += 8) {
    int dd[8];
#pragma unroll
    for (int j = 0; j < 8; ++j) dd[j] = dst[base_e + t + 512 * (i + j)];
#pragma unroll
    for (int j = 0; j < 8; ++j) atomicAdd(&hist[dd[j] - base_n], 1);
  }
  __syncthreads();
  int a[4], ssum = 0;
#pragma unroll
  for (int i = 0; i < 4; ++i) { a[i] = hist[4 * t + i]; ssum += a[i]; }
  {
    int lane = t & 63, w = t >> 6;   // 8 waves
    int v = ssum;
#pragma unroll
    for (int o = 1; o < 64; o <<= 1) {
      int nv = __shfl_up(v, o);
      if (lane >= o) v += nv;
    }
    if (lane == 63) wsum8[w] = v;
    __syncthreads();
    if (t == 0) {
      int accv = 0;
      for (int i = 0; i < 8; ++i) { int tmp = wsum8[i]; wsum8[i] = accv; accv += tmp; }
    }
    __syncthreads();
    int run = wsum8[w] + v - ssum;
#pragma unroll
    for (int i = 0; i < 4; ++i) {
      int n = 4 * t + i;
      off[base_n + n] = base_e + run;
      hist[n] = run;                 // LDS cursor (own bins only: safe)
      float d0 = 1.f + (float)a[i];  // deg = 1 + indegree (layer-0 masks = 1)
      float di0 = 1.f / sqrtf(d0);
      dinv[base_n + n] = di0;
      ds[base_n + n] = di0;
      sws[base_n + n] = di0 * di0;
      run += a[i];
    }
    if (g == B_ - 1 && t == 0) off[NT] = E_;
  }
  __syncthreads();
  for (int i = 0; i < EPG / 512; i += 8) {
    int dd[8], ss[8];
#pragma unroll
    for (int j = 0; j < 8; ++j) {
      int e = base_e + t + 512 * (i + j);
      dd[j] = dst[e];
      ss[j] = src[e];
    }
#pragma unroll
    for (int j = 0; j < 8; ++j) {
      int slot = atomicAdd(&hist[dd[j] - base_n], 1);
      srcp[base_e + slot] = ss[j];
    }
  }
}

// ---- norm role (512 thr, 64 nodes x 8 lanes), piggybacked on mm(l+1) ------
__device__ void norm_body(const int* __restrict__ off,
                          const int* __restrict__ nsrcp,
                          const int* __restrict__ ndend,
                          const float* __restrict__ kpmask,
                          const float* __restrict__ scale,
                          float* __restrict__ dinv,
                          float* __restrict__ ds,
                          float* __restrict__ sws,
                          const int* __restrict__ nkept,
                          int nkshift, int nbpgsh, int nb) {
  int q = relabel(nb, nbpgsh) * 64 + ((int)threadIdx.x >> 3);
  int g = q >> nkshift;
  int node = nkept[g * N_ + (q - (g << nkshift))];
  const int lane = threadIdx.x & 7;
  int s = off[node];
  int en = ndend ? ndend[node] : off[node + 1];
  float d = (lane == 0) ? 1.f : 0.f;
  for (int j = s + lane; j < en; j += 8) d += kpmask[nsrcp[j]];
#pragma unroll
  for (int o = 4; o >= 1; o >>= 1) d += __shfl_down(d, o, 8);
  if (lane == 0) {
    float di = 1.f / sqrtf(d);
    float sc = scale[node];
    dinv[node] = di;
    ds[node] = di * sc;
    sws[node] = di * di * sc;
  }
}

// ---- compact role (512 thr, 64 nodes x 8 lanes), piggybacked on mm(l+1) ---
// Filters node's source list by dinv[s]>0 into srcOut (same segment starts);
// writes dendOut[node]. Race with norm's dinv rewrite is benign (old and new
// values both positive for kept nodes; dropped are 0 from pool).
__device__ void compact_body(const int* __restrict__ off,
                             const int* __restrict__ srcIn,
                             const int* __restrict__ dendIn,
                             const float* __restrict__ alive,
                             int* __restrict__ srcOut,
                             int* __restrict__ dendOut,
                             const int* __restrict__ nkept,
                             int nkshift, int nbpgsh, int nb) {
  int q = relabel(nb, nbpgsh) * 64 + ((int)threadIdx.x >> 3);
  int g = q >> nkshift;
  int node = nkept[g * N_ + (q - (g << nkshift))];
  const int sub = threadIdx.x & 7;
  const int grp8 = ((int)threadIdx.x & 63) >> 3;
  int s = off[node];
  int en = dendIn ? dendIn[node] : off[node + 1];
  int cnt = 0;
  for (int j = s; j < en; j += 8) {
    int idx = j + sub;
    int sv = 0;
    bool valid = (idx < en);
    if (valid) sv = srcIn[idx];
    bool pred = valid && (alive[sv] > 0.f);
    unsigned long long b = __ballot(pred);
    unsigned m8 = (unsigned)(b >> (grp8 * 8)) & 0xFFu;
    int rank = __popc(m8 & ((1u << sub) - 1u));
    if (pred) srcOut[s + cnt + rank] = sv;
    cnt += __popc(m8);
  }
  if (sub == 0) dendOut[node] = s + cnt;
}

// ---- dense matmul + fused readout; roles: [csr | mm | norm | compact] ------
__global__ __launch_bounds__(512) void k_matmul(const float* __restrict__ A,
                                                const float* __restrict__ W,
                                                float* __restrict__ C,
                                                const int* __restrict__ kept,
                                                int kshift, int bpgsh, int mmBlocks,
                                                const float* __restrict__ scaleArr,
                                                float* __restrict__ pmx,
                                                float* __restrict__ psm,
                                                const int* __restrict__ src,
                                                const int* __restrict__ dst,
                                                int* __restrict__ off,
                                                int* __restrict__ srcp,
                                                float* __restrict__ dinvW,
                                                float* __restrict__ dsW,
                                                float* __restrict__ swsW,
                                                int csrBlocks,
                                                const float* __restrict__ kpmask,
                                                const int* __restrict__ nkept,
                                                int nkshift, int nbpgsh,
                                                const int* __restrict__ nsrcp,
                                                const int* __restrict__ ndend,
                                                int normBlocks,
                                                int* __restrict__ csrcOut,
                                                int* __restrict__ cdendOut) {
  __shared__ float Ast[2][32 * AST];   // 33.8 KB
  __shared__ float Ws[2][32 * 128];    // 32.8 KB
  __shared__ int rowid[128];
  __shared__ float rsc[128];
  if ((int)blockIdx.x < csrBlocks) {
    csr_build(src, dst, off, srcp, dinvW, dsW, swsW, (int*)&Ast[0][0]);
    return;
  }
  if ((int)blockIdx.x >= csrBlocks + mmBlocks) {
    int rb = (int)blockIdx.x - csrBlocks - mmBlocks;
    if (rb < normBlocks) {
      norm_body(off, nsrcp, ndend, kpmask, scaleArr, dinvW, dsW, swsW, nkept,
                nkshift, nbpgsh, rb);
    } else {
      compact_body(off, nsrcp, ndend, dinvW, csrcOut, cdendOut, nkept,
                   nkshift, nbpgsh, rb - normBlocks);
    }
    return;
  }
  const int tid = threadIdx.x;   // 0..511
  const int tile = relabel((int)blockIdx.x - csrBlocks, bpgsh);
  if (kept) {
    if (tid < 128) {
      int q = tile * 128 + tid;
      int g = q >> kshift;
      int row = kept[g * N_ + (q - (g << kshift))];
      rowid[tid] = row;
      rsc[tid] = scaleArr[row];
    }
    __syncthreads();
  }
  const int rowq = tid >> 4;   // 0..31: rows 4*rowq..+3
  const int colq = tid & 15;   // cols {4c..4c+3, 64+4c..+3}
  float4 va[2], vw[2];
#pragma unroll
  for (int i = 0; i < 2; ++i) {
    int idx = tid + 512 * i;
    int row = idx >> 3, f4 = idx & 7;
    int grw = kept ? rowid[row] : tile * 128 + row;
    va[i] = *(const float4*)&A[(size_t)grw * 128 + 4 * f4];
  }
#pragma unroll
  for (int i = 0; i < 2; ++i) {
    int idx = tid + 512 * i;
    int kk = idx >> 5, cf = idx & 31;
    vw[i] = *(const float4*)&W[(size_t)kk * 128 + 4 * cf];
  }
#pragma unroll
  for (int i = 0; i < 2; ++i) {
    int idx = tid + 512 * i;
    int row = idx >> 3, f4 = idx & 7;
    Ast[0][(4 * f4 + 0) * AST + row] = va[i].x;
    Ast[0][(4 * f4 + 1) * AST + row] = va[i].y;
    Ast[0][(4 * f4 + 2) * AST + row] = va[i].z;
    Ast[0][(4 * f4 + 3) * AST + row] = va[i].w;
  }
#pragma unroll
  for (int i = 0; i < 2; ++i) {
    int idx = tid + 512 * i;
    int kk = idx >> 5, cf = idx & 31;
    *(float4*)&Ws[0][kk * 128 + 4 * cf] = vw[i];
  }
  __syncthreads();
  float acc[4][8] = {};
  for (int c = 0; c < 4; ++c) {
    int cur = c & 1;
    if (c < 3) {
      int k0n = 32 * (c + 1);
#pragma unroll
      for (int i = 0; i < 2; ++i) {
        int idx = tid + 512 * i;
        int row = idx >> 3, f4 = idx & 7;
        int grw = kept ? rowid[row] : tile * 128 + row;
        va[i] = *(const float4*)&A[(size_t)grw * 128 + k0n + 4 * f4];
      }
#pragma unroll
      for (int i = 0; i < 2; ++i) {
        int idx = tid + 512 * i;
        int kk = idx >> 5, cf = idx & 31;
        vw[i] = *(const float4*)&W[(size_t)(k0n + kk) * 128 + 4 * cf];
      }
    }
#pragma unroll 2
    for (int kk = 0; kk < 32; ++kk) {
      float4 a0 = *(const float4*)&Ast[cur][kk * AST + 4 * rowq];
      float4 w0 = *(const float4*)&Ws[cur][kk * 128 + 4 * colq];
      float4 w1 = *(const float4*)&Ws[cur][kk * 128 + 64 + 4 * colq];
      float a[4] = {a0.x, a0.y, a0.z, a0.w};
      float w[8] = {w0.x, w0.y, w0.z, w0.w, w1.x, w1.y, w1.z, w1.w};
#pragma unroll
      for (int r = 0; r < 4; ++r)
#pragma unroll
        for (int cc = 0; cc < 8; ++cc) acc[r][cc] += a[r] * w[cc];
    }
    // fused readout of this chunk's 32 feats from the staged tile
    if (kept) {
      int kkf = tid >> 4;            // feat within chunk, 0..31
      int r0 = (tid & 15) * 8;       // 8-row slice per thread
      float mxv = -INFINITY, smv = 0.f;
#pragma unroll
      for (int rr = 0; rr < 8; rr += 4) {
        float4 av = *(const float4*)&Ast[cur][kkf * AST + r0 + rr];
        float4 s4 = *(const float4*)&rsc[r0 + rr];
        float v0 = av.x * s4.x, v1 = av.y * s4.y;
        float v2 = av.z * s4.z, v3 = av.w * s4.w;
        mxv = fmaxf(fmaxf(fmaxf(mxv, v0), fmaxf(v1, v2)), v3);
        smv += v0 + v1 + v2 + v3;
      }
#pragma unroll
      for (int o = 8; o >= 1; o >>= 1) {
        mxv = fmaxf(mxv, __shfl_down(mxv, o, 16));
        smv += __shfl_down(smv, o, 16);
      }
      if ((tid & 15) == 0) {
        pmx[(size_t)tile * 128 + 32 * c + kkf] = mxv;
        psm[(size_t)tile * 128 + 32 * c + kkf] = smv;
      }
    }
    if (c < 3) {
      int nxt = cur ^ 1;
#pragma unroll
      for (int i = 0; i < 2; ++i) {
        int idx = tid + 512 * i;
        int row = idx >> 3, f4 = idx & 7;
        Ast[nxt][(4 * f4 + 0) * AST + row] = va[i].x;
        Ast[nxt][(4 * f4 + 1) * AST + row] = va[i].y;
        Ast[nxt][(4 * f4 + 2) * AST + row] = va[i].z;
        Ast[nxt][(4 * f4 + 3) * AST + row] = va[i].w;
      }
#pragma unroll
      for (int i = 0; i < 2; ++i) {
        int idx = tid + 512 * i;
        int kk = idx >> 5, cf = idx & 31;
        *(float4*)&Ws[nxt][kk * 128 + 4 * cf] = vw[i];
      }
      __syncthreads();
    }
  }
#pragma unroll
  for (int r = 0; r < 4; ++r) {
    int grw = kept ? rowid[4 * rowq + r] : tile * 128 + 4 * rowq + r;
    float* Crow = &C[(size_t)grw * 128];
    *(float4*)&Crow[4 * colq] = make_float4(acc[r][0], acc[r][1], acc[r][2], acc[r][3]);
    *(float4*)&Crow[64 + 4 * colq] = make_float4(acc[r][4], acc[r][5], acc[r][6], acc[r][7]);
  }
}

// ---- feature aggregation + bias + relu + fused score matvec (R23 guard) ----
__global__ __launch_bounds__(256) void k_agg(const float4* __restrict__ t4,
                                             const int* __restrict__ off,
                                             const int* __restrict__ srcp,
                                             const int* __restrict__ dend,
                                             const float* __restrict__ dinv,
                                             const float* __restrict__ ds,
                                             const float* __restrict__ sws,
                                             const float* __restrict__ bias,
                                             const float* __restrict__ Wp,
                                             float4* __restrict__ h4,
                                             float* __restrict__ t1,
                                             const int* __restrict__ kept,
                                             int kshift, int bpgsh) {
  int q = relabel(blockIdx.x, bpgsh) * 8 + (threadIdx.x >> 5);
  int node;
  if (kept) {
    int g = q >> kshift;
    node = kept[g * N_ + (q - (g << kshift))];
  } else {
    node = q;
  }
  const int lane = threadIdx.x & 31;
  const float dvi = dinv[node];
  float sw = sws[node];
  float4 self = t4[(size_t)node * 32 + lane];
  float4 acc = make_float4(sw * self.x, sw * self.y, sw * self.z, sw * self.w);
  int s = off[node];
  int en = dend ? dend[node] : off[node + 1];
  int j = s;
  for (; j + 8 <= en; j += 8) {
    int sv[8];
    float cv[8];
#pragma unroll
    for (int i = 0; i < 8; ++i) sv[i] = srcp[j + i];
#pragma unroll
    for (int i = 0; i < 8; ++i) cv[i] = ds[sv[i]] * dvi;
#pragma unroll
    for (int i = 0; i < 8; ++i) {
      if (cv[i] != 0.f) {
        float4 r = t4[(size_t)sv[i] * 32 + lane];
        acc.x += cv[i] * r.x; acc.y += cv[i] * r.y;
        acc.z += cv[i] * r.z; acc.w += cv[i] * r.w;
      }
    }
  }
  for (; j < en; ++j) {
    int s0 = srcp[j];
    float c0 = ds[s0] * dvi;
    if (c0 != 0.f) {
      float4 r0 = t4[(size_t)s0 * 32 + lane];
      acc.x += c0 * r0.x; acc.y += c0 * r0.y; acc.z += c0 * r0.z; acc.w += c0 * r0.w;
    }
  }
  float4 b4 = ((const float4*)bias)[lane];
  acc.x = fmaxf(acc.x + b4.x, 0.f);
  acc.y = fmaxf(acc.y + b4.y, 0.f);
  acc.z = fmaxf(acc.z + b4.z, 0.f);
  acc.w = fmaxf(acc.w + b4.w, 0.f);
  h4[(size_t)node * 32 + lane] = acc;
  float4 wp = ((const float4*)Wp)[lane];
  float part = acc.x * wp.x + acc.y * wp.y + acc.z * wp.z + acc.w * wp.w;
#pragma unroll
  for (int o = 16; o > 0; o >>= 1) part += __shfl_down(part, o, 32);
  if (lane == 0) t1[node] = part;
}

// ---- score aggregation: 8 lanes/node ---------------------------------------
__global__ __launch_bounds__(256) void k_score(const float* __restrict__ t1,
                                               const int* __restrict__ off,
                                               const int* __restrict__ srcp,
                                               const int* __restrict__ dend,
                                               const float* __restrict__ dinv,
                                               const float* __restrict__ bp,
                                               float* __restrict__ raw,
                                               const int* __restrict__ kept,
                                               int kshift, int bpgsh) {
  int q = relabel(blockIdx.x, bpgsh) * 32 + (threadIdx.x >> 3);
  int node;
  if (kept) {
    int g = q >> kshift;
    node = kept[g * N_ + (q - (g << kshift))];
  } else {
    node = q;
  }
  const int lane = threadIdx.x & 7;
  int s = off[node];
  int en = dend ? dend[node] : off[node + 1];
  float a = 0.f;
  for (int j = s + lane; j < en; j += 8) {
    int sl = srcp[j];
    a += dinv[sl] * t1[sl];
  }
#pragma unroll
  for (int o = 4; o >= 1; o >>= 1) a += __shfl_down(a, o, 8);
  if (lane == 0) {
    float di = dinv[node];
    raw[node] = di * di * t1[node] + di * a + bp[0];
  }
}

// ---- pool: 3-pass radix top-k + compact + mask writes (+readout+head) ------
__global__ __launch_bounds__(1024) void k_pool(const float* __restrict__ raw,
                                               float* __restrict__ dinv,
                                               float* __restrict__ ds,
                                               float* __restrict__ sws,
                                               float* __restrict__ scale,
                                               float* __restrict__ kpmask,
                                               int* __restrict__ kept,
                                               const float4* __restrict__ h4,
                                               float invk, int k,
                                               const int* __restrict__ inKept, int klen,
                                               const float* __restrict__ pmxA,
                                               const float* __restrict__ psmA,
                                               const float* __restrict__ pmxB,
                                               const float* __restrict__ psmB,
                                               const float* __restrict__ hW1,
                                               const float* __restrict__ hb1,
                                               const float* __restrict__ hW2,
                                               const float* __restrict__ hb2,
                                               const float* __restrict__ hW3,
                                               const float* __restrict__ hb3,
                                               float* __restrict__ out) {
  __shared__ float st1[2048];       // scale after selection (readout)
  __shared__ float skp[2048];
  __shared__ int skept[1024];
  __shared__ unsigned rephist[4096];  // radix bins; reused as red[] in readout
  __shared__ unsigned ebits[64];
  __shared__ int wsum[16];
  __shared__ unsigned bc_digit, bc_prev;
  __shared__ float gr[256], o1[128], o2[64], o3[NCLS];
  const int g = (blockIdx.x & 7) + 8 * (blockIdx.x >> 3);
  const int t = threadIdx.x;
  const int base = g * N_;
  st1[t] = 0.f;
  st1[t + 1024] = 0.f;
  skp[t] = 0.f;
  skp[t + 1024] = 0.f;
  if (t < 64) ebits[t] = 0u;
  __syncthreads();
  int nodeq[2] = {-1, -1};
  float rawv[2] = {0.f, 0.f};
  unsigned key[2] = {0xFFFFFFFFu, 0xFFFFFFFFu};
#pragma unroll
  for (int q = 0; q < 2; ++q) {
    int i = t + q * 1024;
    if (i >= klen) continue;
    int n = inKept ? (inKept[base + i] - base) : i;
    nodeq[q] = n;
    float r = raw[base + n];
    rawv[q] = r;
    unsigned u = __float_as_uint(r);
    u = (u & 0x80000000u) ? ~u : (u | 0x80000000u);
    u = ~u;  // descending
    key[q] = u;
  }
  // 3-pass radix select of k-th largest: bits [31:21], [20:10], [9:0].
  unsigned prefix = 0u, rem = (unsigned)k;
  const int SH0 = 21, SH1 = 10, SH2 = 0;
  for (int p = 0; p < 3; ++p) {
    const int shift = (p == 0) ? SH0 : (p == 1 ? SH1 : SH2);
    const int nb = (p == 2) ? 1024 : 2048;
    const unsigned mask = (p == 0) ? 0u
                        : (p == 1 ? (0xFFFFFFFFu << SH0) : (0xFFFFFFFFu << SH1));
    rephist[t] = 0u;
    rephist[t + 1024] = 0u;
    __syncthreads();
#pragma unroll
    for (int q = 0; q < 2; ++q)
      if (nodeq[q] >= 0 && (key[q] & mask) == prefix)
        atomicAdd(&rephist[(key[q] >> shift) & (unsigned)(nb - 1)], 1u);
    __syncthreads();
    unsigned b0, b1;
    if (nb == 2048) { b0 = rephist[2 * t]; b1 = rephist[2 * t + 1]; }
    else           { b0 = rephist[t];     b1 = 0u; }
    unsigned ps = b0 + b1;
    {
      int lane = t & 63, w = t >> 6;
      unsigned v = ps;
#pragma unroll
      for (int o = 1; o < 64; o <<= 1) {
        unsigned nv = __shfl_up(v, o);
        if (lane >= o) v += nv;
      }
      if (lane == 63) wsum[w] = (int)v;
      __syncthreads();
      if (t == 0) {
        int accv = 0;
        for (int i = 0; i < 16; ++i) { int tmp = wsum[i]; wsum[i] = accv; accv += tmp; }
      }
      __syncthreads();
      unsigned exc = (unsigned)wsum[w] + v - ps;
      if (exc < rem && exc + b0 >= rem) {
        bc_digit = (unsigned)((nb == 2048) ? 2 * t : t);
        bc_prev = exc;
      }
      if (nb == 2048 && exc + b0 < rem && exc + b0 + b1 >= rem) {
        bc_digit = (unsigned)(2 * t + 1);
        bc_prev = exc + b0;
      }
    }
    __syncthreads();
    prefix |= bc_digit << shift;
    rem -= bc_prev;
  }
  const unsigned Tkey = prefix;
  const int need = (int)rem;  // ties, lowest index first
#pragma unroll
  for (int q = 0; q < 2; ++q) {
    int n = nodeq[q];
    if (n >= 0 && key[q] == Tkey) atomicOr(&ebits[n >> 5], 1u << (n & 31));
  }
  __syncthreads();
#pragma unroll
  for (int q = 0; q < 2; ++q) {
    int n = nodeq[q];
    if (n < 0) continue;
    float kp;
    if (key[q] < Tkey) {
      kp = 1.f;
    } else if (key[q] == Tkey) {
      int w = n >> 5;
      int rank = __popc(ebits[w] & ((1u << (n & 31)) - 1u));
      for (int u = 0; u < w; ++u) rank += __popc(ebits[u]);
      kp = (rank < need) ? 1.f : 0.f;
    } else {
      kp = 0.f;
    }
    skp[n] = kp;
    float sc = kp * tanhf(rawv[q]);
    st1[n] = sc;
    scale[base + n] = sc;
    kpmask[base + n] = kp;
    if (kp == 0.f) {            // dropped: zero masks for next layer's gathers
      dinv[base + n] = 0.f;
      ds[base + n] = 0.f;
      sws[base + n] = 0.f;
    }
  }
  __syncthreads();
  // compacted kept list -> global + LDS
  {
    int lane = t & 63, w = t >> 6;
    int a0 = (int)skp[2 * t], a1 = (int)skp[2 * t + 1];
    int ps = a0 + a1;
    int v = ps;
#pragma unroll
    for (int o = 1; o < 64; o <<= 1) {
      int nv = __shfl_up(v, o);
      if (lane >= o) v += nv;
    }
    if (lane == 63) wsum[w] = v;
    __syncthreads();
    if (t == 0) {
      int accv = 0;
      for (int i = 0; i < 16; ++i) { int tmp = wsum[i]; wsum[i] = accv; accv += tmp; }
    }
    __syncthreads();
    int excl = wsum[w] + v - ps;
    if (a0) { kept[base + excl] = base + 2 * t; skept[excl] = base + 2 * t; }
    if (a1) { kept[base + excl + a0] = base + 2 * t + 1; skept[excl + a0] = base + 2 * t + 1; }
  }
  if (!out) return;
  __syncthreads();
  // layer-3 readout over kept list
  const int lane = t & 31, ng = t >> 5;
  float4 mx = make_float4(-INFINITY, -INFINITY, -INFINITY, -INFINITY);
  float4 sm = make_float4(0.f, 0.f, 0.f, 0.f);
  for (int i = ng; i < k; i += 32) {
    int node = skept[i];
    float sc = st1[node - base];
    float4 v = h4[(size_t)node * 32 + lane];
    v.x *= sc; v.y *= sc; v.z *= sc; v.w *= sc;
    mx.x = fmaxf(mx.x, v.x); mx.y = fmaxf(mx.y, v.y);
    mx.z = fmaxf(mx.z, v.z); mx.w = fmaxf(mx.w, v.w);
    sm.x += v.x; sm.y += v.y; sm.z += v.z; sm.w += v.w;
  }
  float4* red = (float4*)rephist;
  for (int d = 16; d >= 1; d >>= 1) {
    if (ng >= d && ng < 2 * d) {
      red[(ng - d) * 32 + lane] = mx;
      red[512 + (ng - d) * 32 + lane] = sm;
    }
    __syncthreads();
    if (ng < d) {
      float4 omx = red[ng * 32 + lane];
      float4 osm = red[512 + ng * 32 + lane];
      mx.x = fmaxf(mx.x, omx.x); mx.y = fmaxf(mx.y, omx.y);
      mx.z = fmaxf(mx.z, omx.z); mx.w = fmaxf(mx.w, omx.w);
      sm.x += osm.x; sm.y += osm.y; sm.z += osm.z; sm.w += osm.w;
    }
    __syncthreads();
  }
  if (ng == 0) {
    gr[4 * lane + 0] = mx.x;
    gr[4 * lane + 1] = mx.y;
    gr[4 * lane + 2] = mx.z;
    gr[4 * lane + 3] = mx.w;
    gr[128 + 4 * lane + 0] = sm.x * invk;
    gr[128 + 4 * lane + 1] = sm.y * invk;
    gr[128 + 4 * lane + 2] = sm.z * invk;
    gr[128 + 4 * lane + 3] = sm.w * invk;
  }
  __syncthreads();
  // fused MLP head + log_softmax
  if (t < 128) {
    float mxA = -INFINITY, smA = 0.f;
#pragma unroll
    for (int p = 0; p < 8; ++p) {
      mxA = fmaxf(mxA, pmxA[(size_t)(g * 8 + p) * 128 + t]);
      smA += psmA[(size_t)(g * 8 + p) * 128 + t];
    }
    float mxB = -INFINITY, smB = 0.f;
#pragma unroll
    for (int p = 0; p < 4; ++p) {
      mxB = fmaxf(mxB, pmxB[(size_t)(g * 4 + p) * 128 + t]);
      smB += psmB[(size_t)(g * 4 + p) * 128 + t];
    }
    gr[t] += mxA + mxB;
    gr[t + 128] += smA * (1.f / 1024.f) + smB * (1.f / 512.f);
  }
  __syncthreads();
  if (t < 128) {
    float a = hb1[t];
    for (int kk = 0; kk < 256; ++kk) a += gr[kk] * hW1[kk * 128 + t];
    o1[t] = fmaxf(a, 0.f);
  }
  __syncthreads();
  if (t < 64) {
    float a2 = hb2[t];
    for (int kk = 0; kk < 128; ++kk) a2 += o1[kk] * hW2[kk * 64 + t];
    o2[t] = fmaxf(a2, 0.f);
  }
  __syncthreads();
  if (t < NCLS) {
    float a3 = hb3[t];
    for (int kk = 0; kk < 64; ++kk) a3 += o2[kk] * hW3[kk * NCLS + t];
    o3[t] = a3;
  }
  __syncthreads();
  if (t == 0) {
    float m = -INFINITY;
    for (int c = 0; c < NCLS; ++c) m = fmaxf(m, o3[c]);
    float sum = 0.f;
    for (int c = 0; c < NCLS; ++c) sum += expf(o3[c] - m);
    float lse = logf(sum);
    for (int c = 0; c < NCLS; ++c) out[g * NCLS + c] = o3[c] - m - lse;
  }
}

}  // namespace

extern "C" void kernel_launch(void* const* d_in, const int* in_sizes, int n_in,
                              void* d_out, int out_size, void* d_ws, size_t ws_size,
                              hipStream_t stream) {
  const float* x = (const float*)d_in[0];
  const int* ei = (const int*)d_in[1];
  const int* src = ei;
  const int* dst = ei + E_;
  const float* Wl[3]  = {(const float*)d_in[3], (const float*)d_in[7], (const float*)d_in[11]};
  const float* bl[3]  = {(const float*)d_in[4], (const float*)d_in[8], (const float*)d_in[12]};
  const float* Wpl[3] = {(const float*)d_in[5], (const float*)d_in[9], (const float*)d_in[13]};
  const float* bpl[3] = {(const float*)d_in[6], (const float*)d_in[10], (const float*)d_in[14]};
  const float* l1W = (const float*)d_in[15];
  const float* l1b = (const float*)d_in[16];
  const float* l2W = (const float*)d_in[17];
  const float* l2b = (const float*)d_in[18];
  const float* l3W = (const float*)d_in[19];
  const float* l3b = (const float*)d_in[20];

  char* p = (char*)d_ws;
  auto alloc = [&](size_t bytes) -> void* {
    void* r = (void*)p;
    p += (bytes + 255) & ~size_t(255);
    return r;
  };
  float* h      = (float*)alloc((size_t)NT * 128 * 4);
  float* t      = (float*)alloc((size_t)NT * 128 * 4);
  float* dinv   = (float*)alloc(NT * 4);
  float* ds     = (float*)alloc(NT * 4);
  float* sws    = (float*)alloc(NT * 4);
  float* scale  = (float*)alloc(NT * 4);
  float* t1     = (float*)alloc(NT * 4);
  float* raw    = (float*)alloc(NT * 4);
  float* kpmask = (float*)alloc(NT * 4);
  int*   srcp   = (int*)alloc(E_ * 4);
  int*   srcpB  = (int*)alloc(E_ * 4);
  int*   dend1  = (int*)alloc(NT * 4);
  int*   dend2  = (int*)alloc(NT * 4);
  int*   off    = (int*)alloc((NT + 1) * 4);
  int*   kept0  = (int*)alloc(NT * 4);
  int*   kept1  = (int*)alloc(NT * 4);
  int*   kept2  = (int*)alloc(NT * 4);
  float* pmxA   = (float*)alloc(256 * 128 * 4);
  float* psmA   = (float*)alloc(256 * 128 * 4);
  float* pmxB   = (float*)alloc(128 * 128 * 4);
  float* psmB   = (float*)alloc(128 * 128 * 4);

  int* keptL[3] = {kept0, kept1, kept2};
  const int K[3] = {1024, 512, 256};
  const int KSH[3] = {10, 9, 8};
  float* pmxL[3] = {nullptr, pmxA, pmxB};
  float* psmL[3] = {nullptr, psmA, psmB};
  // era-l edge lists: l0 = srcp (full, dend NULL); l1 = srcpB + dend1;
  // l2 = srcp (reused) + dend2.
  const int* srcL[3]  = {srcp, srcpB, srcp};
  const int* dendL[3] = {nullptr, dend1, dend2};
  int* srcOutL[2]  = {srcpB, srcp};     // compact(l) writes era l+1
  int* dendOutL[2] = {dend1, dend2};

  const float* inF = x;
  for (int l = 0; l < 3; ++l) {
    const int* inKept = (l == 0) ? nullptr : keptL[l - 1];
    int inKsh = (l == 0) ? 11 : KSH[l - 1];
    int nrows = (l == 0) ? NT : B_ * K[l - 1];
    int mmB = nrows / 128;
    int mm_bpgsh = (l == 0) ? 4 : (l == 1 ? 3 : 2);   // 512/256/128 mm blocks
    int ag_bpgsh = (l == 0) ? 8 : (l == 1 ? 7 : 6);   // 8192/4096/2048 blocks
    int sc_bpgsh = (l == 0) ? 6 : (l == 1 ? 5 : 4);   // 2048/1024/512 blocks
    int csrB = (l == 0) ? B_ : 0;                     // csr piggybacks on mm0
    // norm+compact of layer l-1 piggyback on mm(l): 64 nodes/block each
    int normB = (l == 0) ? 0 : (B_ * K[l - 1]) / 64;  // 512 / 256 blocks
    int nbpgsh = (l == 1) ? 4 : 3;                    // 16 / 8 blocks per graph
    int compB = normB;                                // same geometry
    int klen = (l == 0) ? N_ : K[l - 1];
    bool last = (l == 2);
    k_matmul<<<csrB + mmB + normB + compB, 512, 0, stream>>>(
        inF, Wl[l], t, inKept, inKsh, mm_bpgsh, mmB, scale, pmxL[l], psmL[l],
        src, dst, off, srcp, dinv, ds, sws, csrB,
        kpmask, inKept, inKsh, nbpgsh,
        (l == 0) ? nullptr : srcL[l - 1], (l == 0) ? nullptr : dendL[l - 1],
        normB,
        (l == 0) ? nullptr : srcOutL[l - 1],
        (l == 0) ? nullptr : dendOutL[l - 1]);
    k_agg<<<nrows / 8, 256, 0, stream>>>((const float4*)t, off, srcL[l], dendL[l],
                                         dinv, ds, sws, bl[l], Wpl[l],
                                         (float4*)h, t1, inKept, inKsh, ag_bpgsh);
    k_score<<<nrows / 32, 256, 0, stream>>>(t1, off, srcL[l], dendL[l], dinv,
                                            bpl[l], raw, inKept, inKsh, sc_bpgsh);
    k_pool<<<B_, 1024, 0, stream>>>(raw, dinv, ds, sws, scale, kpmask,
                                    keptL[l], (const float4*)h,
                                    1.f / (float)K[l], K[l], inKept, klen,
                                    last ? pmxA : nullptr, last ? psmA : nullptr,
                                    last ? pmxB : nullptr, last ? psmB : nullptr,
                                    l1W, l1b, l2W, l2b, l3W, l3b,
                                    last ? (float*)d_out : nullptr);
    inF = h;
  }
}